// Round 1
// 415.308 us; speedup vs baseline: 1.0221x; 1.0221x over previous
//
#include <hip/hip_runtime.h>
#include <math.h>

#define BDIM 2
#define SDIM 4096
#define DMODEL 512
#define NHEAD 8
#define DHEAD 64
#define MROWS (BDIM * SDIM)  // 8192

typedef __attribute__((ext_vector_type(8))) short short8;
typedef __attribute__((ext_vector_type(4))) float f32x4;

#define MFMA16(a, b, c) __builtin_amdgcn_mfma_f32_16x16x32_bf16((a), (b), (c), 0, 0, 0)
#define EXP2F(x) __builtin_amdgcn_exp2f(x)

#define SCALE2 0.18033688011112042f  // 0.125 * log2(e)
#define MASKMUL -1.442695040e9f      // -1e9 * log2(e)
#define M0C 16.0f                    // fixed softmax shift (2^-M0 cancels in O/l)

#define GLOAD_LDS16(g, l)                                                     \
  __builtin_amdgcn_global_load_lds(                                           \
      (const __attribute__((address_space(1))) void*)(g),                     \
      (__attribute__((address_space(3))) void*)(l), 16, 0, 0)

// Truncation split: x = h + l with h = top 16 bits (exact subtraction).
__device__ inline void bf16_split(float x, short& h, short& l) {
  unsigned u = __float_as_uint(x);
  h = (short)(u >> 16);
  float hf = __uint_as_float(u & 0xffff0000u);
  l = (short)(__float_as_uint(x - hf) >> 16);
}

// ---------------------------------------------------------------------------
// One-shot weight prep: W[k][n] fp32 -> Wt_h[n][k], Wt_l[n][k] bf16 h/l.
// ---------------------------------------------------------------------------
__global__ __launch_bounds__(256) void wsplit_kernel(
    const float* __restrict__ W0, const float* __restrict__ W1,
    const float* __restrict__ W2, const float* __restrict__ W3,
    short* __restrict__ T0h, short* __restrict__ T0l, short* __restrict__ T1h,
    short* __restrict__ T1l, short* __restrict__ T2h, short* __restrict__ T2l,
    short* __restrict__ T3h, short* __restrict__ T3l) {
  __shared__ short Th[64 * 72], Tl[64 * 72];
  const int tid = threadIdx.x;
  const int k0 = blockIdx.x * 64;
  const int n0 = blockIdx.y * 64;
  const int z = blockIdx.z;
  const float* W = (z == 0) ? W0 : (z == 1) ? W1 : (z == 2) ? W2 : W3;
  short* Oh = (z == 0) ? T0h : (z == 1) ? T1h : (z == 2) ? T2h : T3h;
  short* Ol = (z == 0) ? T0l : (z == 1) ? T1l : (z == 2) ? T2l : T3l;

  {
    const int r = tid >> 2;
    const int c16 = (tid & 3) * 16;
    short8 h0, h1, l0, l1;
#pragma unroll
    for (int g = 0; g < 2; g++) {
      const f32x4 a = *(const f32x4*)(W + (size_t)(k0 + r) * DMODEL + n0 + c16 + g * 8);
      const f32x4 b = *(const f32x4*)(W + (size_t)(k0 + r) * DMODEL + n0 + c16 + g * 8 + 4);
      short8& hh = g ? h1 : h0;
      short8& ll = g ? l1 : l0;
#pragma unroll
      for (int j = 0; j < 4; j++) {
        short x, y;
        bf16_split(a[j], x, y);
        hh[j] = x;
        ll[j] = y;
        bf16_split(b[j], x, y);
        hh[4 + j] = x;
        ll[4 + j] = y;
      }
    }
    *(short8*)&Th[r * 72 + c16] = h0;
    *(short8*)&Th[r * 72 + c16 + 8] = h1;
    *(short8*)&Tl[r * 72 + c16] = l0;
    *(short8*)&Tl[r * 72 + c16 + 8] = l1;
  }
  __syncthreads();
  {
    const int n = tid >> 2;
    const int kc = (tid & 3) * 16;
    short8 h0, h1, l0, l1;
#pragma unroll
    for (int i = 0; i < 8; i++) {
      h0[i] = Th[(kc + i) * 72 + n];
      h1[i] = Th[(kc + 8 + i) * 72 + n];
      l0[i] = Tl[(kc + i) * 72 + n];
      l1[i] = Tl[(kc + 8 + i) * 72 + n];
    }
    short* dh = Oh + (size_t)(n0 + n) * DMODEL + k0 + kc;
    short* dl = Ol + (size_t)(n0 + n) * DMODEL + k0 + kc;
    *(short8*)dh = h0;
    *(short8*)(dh + 8) = h1;
    *(short8*)dl = l0;
    *(short8*)(dl + 8) = l1;
  }
}

// ---------------------------------------------------------------------------
// One-shot activation split: X[M,512] fp32 -> Xh, Xl bf16 (row-major).
// Replaces the per-tile in-GEMM split (was redone once per N-tile).
// ---------------------------------------------------------------------------
__global__ __launch_bounds__(256) void xsplit_kernel(const float* __restrict__ X,
                                                     short* __restrict__ Xh,
                                                     short* __restrict__ Xl) {
  const size_t i = ((size_t)blockIdx.x * 256 + threadIdx.x) * 8;
  const f32x4 a = *(const f32x4*)(X + i);
  const f32x4 b = *(const f32x4*)(X + i + 4);
  short8 h, l;
#pragma unroll
  for (int j = 0; j < 4; j++) {
    short x, y;
    bf16_split(a[j], x, y);
    h[j] = x;
    l[j] = y;
    bf16_split(b[j], x, y);
    h[4 + j] = x;
    l[4 + j] = y;
  }
  *(short8*)(Xh + i) = h;
  *(short8*)(Xl + i) = l;
}

// ---------------------------------------------------------------------------
// MFMA bf16x3 GEMM: out[M,512] = X(split) @ Wt(split)^T + bias.
// BM=64, BN=256 (X read only 2x from HBM), BK=32, 512 thr = 8 waves (2Mx4N),
// wave tile 32x64. LDS double-buffered (80 KB), all staging via
// global_load_lds width 16 (no VGPR round-trip, no staging VALU).
// BK=32 rows are 64 B -> linear layout is bank-conflict-optimal for
// ds_read_b128 (row parity spreads slots); no swizzle needed.
// Prefetch next K-slab before compute; the single __syncthreads per step
// drains loads that had a full compute phase to land.
// MODE 0: fp32 out [M,DM].  MODE 1: bf16 h/l split outputs in [B,H,S,D].
// ---------------------------------------------------------------------------
template <int MODE>
__global__ __launch_bounds__(512, 2) void proj2_kernel(
    const short* __restrict__ Xh, const short* __restrict__ Xl,
    const short* __restrict__ Wth, const short* __restrict__ Wtl,
    const float* __restrict__ bias, float* __restrict__ out,
    short* __restrict__ oh, short* __restrict__ ol) {
  // per buffer (shorts): Ah[64*32]=2048 | Al=2048 | Bh[256*32]=8192 | Bl=8192
  __shared__ short L[2 * 20480];  // 80 KB
  const int tid = threadIdx.x;
  const int lane = tid & 63;
  const int w = tid >> 6;  // 0..7
  const int lane15 = lane & 15;
  const int quad = lane >> 4;
  const int m0 = blockIdx.x * 64;
  const int n0 = blockIdx.y * 256;
  const int wm = (w >> 2) * 32;
  const int wn = (w & 3) * 64;

  // Staging: 2560 16B-chunks/step, 5 wave-instructions per wave.
  // chunk g = (w*5+i)*64 + lane; array boundaries all multiples of 64.
  const short* gp[5];
  int ldso[5];
#pragma unroll
  for (int i = 0; i < 5; i++) {
    const int idx = w * 5 + i;
    const int g = idx * 64 + lane;
    if (g < 512) {  // A: rows of Xh/Xl, 4 chunks per 32-k row
      const short* src = (g < 256) ? Xh : Xl;
      const int a = g & 255;
      gp[i] = src + (size_t)(m0 + (a >> 2)) * DMODEL + (a & 3) * 8;
    } else {  // B: rows of Wth/Wtl
      const int gg = g - 512;
      const short* src = (gg < 1024) ? Wth : Wtl;
      const int a = gg & 1023;
      gp[i] = src + (size_t)(n0 + (a >> 2)) * DMODEL + (a & 3) * 8;
    }
    ldso[i] = idx * 512;  // shorts; wave-uniform (idx uniform per wave)
  }

  f32x4 c[2][4];
#pragma unroll
  for (int mt = 0; mt < 2; mt++)
#pragma unroll
    for (int nt = 0; nt < 4; nt++) c[mt][nt] = (f32x4){0.f, 0.f, 0.f, 0.f};

  constexpr int NT = DMODEL / 32;  // 16 K-steps

  // prologue: issue loads for t=0 into buffer 0
#pragma unroll
  for (int i = 0; i < 5; i++) GLOAD_LDS16(gp[i], &L[ldso[i]]);

  for (int t = 0; t < NT; t++) {
    __syncthreads();  // drains vmcnt: tile t resident; buf^1 free of readers
    if (t + 1 < NT) {
      short* dst = &L[((t + 1) & 1) * 20480];
#pragma unroll
      for (int i = 0; i < 5; i++)
        GLOAD_LDS16(gp[i] + (t + 1) * 32, dst + ldso[i]);
    }
    const short* buf = &L[(t & 1) * 20480];
    short8 ah[2], al[2], bh[4], bl[4];
#pragma unroll
    for (int mt = 0; mt < 2; mt++) {
      const int r = wm + mt * 16 + lane15;
      ah[mt] = *(const short8*)&buf[r * 32 + quad * 8];
      al[mt] = *(const short8*)&buf[2048 + r * 32 + quad * 8];
    }
#pragma unroll
    for (int nt = 0; nt < 4; nt++) {
      const int r = wn + nt * 16 + lane15;
      bh[nt] = *(const short8*)&buf[4096 + r * 32 + quad * 8];
      bl[nt] = *(const short8*)&buf[12288 + r * 32 + quad * 8];
    }
    __builtin_amdgcn_s_setprio(1);
#pragma unroll
    for (int mt = 0; mt < 2; mt++)
#pragma unroll
      for (int nt = 0; nt < 4; nt++) {
        c[mt][nt] = MFMA16(ah[mt], bh[nt], c[mt][nt]);
        c[mt][nt] = MFMA16(ah[mt], bl[nt], c[mt][nt]);
        c[mt][nt] = MFMA16(al[mt], bh[nt], c[mt][nt]);
      }
    __builtin_amdgcn_s_setprio(0);
  }

  // ---- epilogue ----
#pragma unroll
  for (int nt = 0; nt < 4; nt++) {
    const int n = n0 + wn + nt * 16 + lane15;
    const float bb = bias[n];
#pragma unroll
    for (int mt = 0; mt < 2; mt++)
#pragma unroll
      for (int r = 0; r < 4; r++) {
        const int m = m0 + wm + mt * 16 + quad * 4 + r;
        const float val = c[mt][nt][r] + bb;
        if (MODE == 1) {
          const int bidx = m >> 12;
          const int s = m & 4095;
          const int hh = n >> 6;
          const int d = n & 63;
          const size_t off =
              ((size_t)(bidx * NHEAD + hh) * SDIM + s) * DHEAD + d;
          short x, y;
          bf16_split(val, x, y);
          oh[off] = x;
          ol[off] = y;
        } else {
          out[(size_t)m * DMODEL + n] = val;
        }
      }
  }
}

// ---------------------------------------------------------------------------
// V transpose: [B,H,S,D] h/l shorts -> [B,H,D,S]. 64x64 tiles via LDS.
// ---------------------------------------------------------------------------
__global__ __launch_bounds__(256) void vtrans_kernel(
    const short* __restrict__ vh, const short* __restrict__ vl,
    short* __restrict__ vth, short* __restrict__ vtl) {
  __shared__ short Th[64 * 72], Tl[64 * 72];
  const int tid = threadIdx.x;
  const int s0 = blockIdx.x * 64;
  const int h = blockIdx.y;
  const int b = blockIdx.z;
  const size_t base = (size_t)(b * NHEAD + h) * SDIM * DHEAD;

  {
    const int s = tid >> 2;
    const int c = tid & 3;
    const short* srcH = vh + base + (size_t)(s0 + s) * DHEAD + c * 16;
    const short* srcL = vl + base + (size_t)(s0 + s) * DHEAD + c * 16;
    *(short8*)&Th[s * 72 + c * 16] = *(const short8*)srcH;
    *(short8*)&Th[s * 72 + c * 16 + 8] = *(const short8*)(srcH + 8);
    *(short8*)&Tl[s * 72 + c * 16] = *(const short8*)srcL;
    *(short8*)&Tl[s * 72 + c * 16 + 8] = *(const short8*)(srcL + 8);
  }
  __syncthreads();
  {
    const int d = tid & 63;
    const int cw = tid >> 6;
    short8 a0, a1, b0, b1;
#pragma unroll
    for (int i = 0; i < 8; i++) {
      a0[i] = Th[(cw * 16 + i) * 72 + d];
      a1[i] = Th[(cw * 16 + 8 + i) * 72 + d];
      b0[i] = Tl[(cw * 16 + i) * 72 + d];
      b1[i] = Tl[(cw * 16 + 8 + i) * 72 + d];
    }
    short* dstH = vth + base + (size_t)d * SDIM + s0 + cw * 16;
    short* dstL = vtl + base + (size_t)d * SDIM + s0 + cw * 16;
    *(short8*)dstH = a0;
    *(short8*)(dstH + 8) = a1;
    *(short8*)dstL = b0;
    *(short8*)(dstL + 8) = b1;
  }
}

// ---------------------------------------------------------------------------
// Flash attention, bf16x3 MFMA, fixed-shift softmax.
// Changes this round: T14 async-stage (prefetch K/V tile t+1 into regs while
// computing tile t), raw s_barrier + explicit lgkmcnt(0) instead of
// __syncthreads (keeps prefetch loads in flight across the barrier — no
// vmcnt(0) drain), s_setprio around MFMA clusters, ctx emitted pre-split h/l.
// ---------------------------------------------------------------------------
#define KP 72
#define VP 72
#define PP 68

__global__ __launch_bounds__(256, 2) void flash_attn_kernel(
    const short* __restrict__ qhh, const short* __restrict__ qhl,
    const short* __restrict__ khh, const short* __restrict__ khl,
    const short* __restrict__ vth, const short* __restrict__ vtl,
    const float* __restrict__ mask, short* __restrict__ ctxh,
    short* __restrict__ ctxl) {
  __shared__ short Ksh[64 * KP], Ksl[64 * KP];
  __shared__ short Vsh[64 * VP], Vsl[64 * VP];
  __shared__ float Ps[128 * PP];

  const int tid = threadIdx.x;
  const int lane = tid & 63;
  const int w = tid >> 6;
  const int lane15 = lane & 15;
  const int quad = lane >> 4;
  const int q0 = blockIdx.x * 128;
  const int h = blockIdx.y;
  const int b = blockIdx.z;

  const size_t base = (size_t)(b * NHEAD + h) * SDIM * DHEAD;
  const short* Qh = qhh + base;
  const short* Ql = qhl + base;
  const short* Kh = khh + base;
  const short* Kl = khl + base;
  const short* Vh = vth + base;  // [D][S]
  const short* Vl = vtl + base;
  const float* mb = mask + (size_t)b * SDIM;

  short8 qfh[2][2], qfl[2][2];
#pragma unroll
  for (int mt = 0; mt < 2; mt++) {
    const size_t row = q0 + w * 32 + mt * 16 + lane15;
#pragma unroll
    for (int ks = 0; ks < 2; ks++) {
      qfh[mt][ks] = *(const short8*)(Qh + row * DHEAD + ks * 32 + quad * 8);
      qfl[mt][ks] = *(const short8*)(Ql + row * DHEAD + ks * 32 + quad * 8);
    }
  }

  f32x4 o[2][4];
#pragma unroll
  for (int mt = 0; mt < 2; mt++)
#pragma unroll
    for (int dt = 0; dt < 4; dt++) o[mt][dt] = (f32x4){0.f, 0.f, 0.f, 0.f};
  float lr[2][4];
#pragma unroll
  for (int mt = 0; mt < 2; mt++)
#pragma unroll
    for (int r = 0; r < 4; r++) lr[mt][r] = 0.f;

  short8 onesb;
#pragma unroll
  for (int j = 0; j < 8; j++) onesb[j] = (short)0x3F80;  // bf16 1.0

  const int sr = tid >> 2;
  const int sc = (tid & 3) * 16;

  // prologue: prefetch tile 0 into registers
  short8 rg[8];
  rg[0] = *(const short8*)(Kh + (size_t)sr * DHEAD + sc);
  rg[1] = *(const short8*)(Kh + (size_t)sr * DHEAD + sc + 8);
  rg[2] = *(const short8*)(Kl + (size_t)sr * DHEAD + sc);
  rg[3] = *(const short8*)(Kl + (size_t)sr * DHEAD + sc + 8);
  rg[4] = *(const short8*)(Vh + (size_t)sr * SDIM + sc);
  rg[5] = *(const short8*)(Vh + (size_t)sr * SDIM + sc + 8);
  rg[6] = *(const short8*)(Vl + (size_t)sr * SDIM + sc);
  rg[7] = *(const short8*)(Vl + (size_t)sr * SDIM + sc + 8);

  for (int kt = 0; kt < SDIM / 64; kt++) {
    const int k0 = kt * 64;
    // barrier A: every wave finished reading the previous tile's LDS
    __builtin_amdgcn_s_barrier();
    __builtin_amdgcn_sched_barrier(0);
    *(short8*)&Ksh[sr * KP + sc] = rg[0];
    *(short8*)&Ksh[sr * KP + sc + 8] = rg[1];
    *(short8*)&Ksl[sr * KP + sc] = rg[2];
    *(short8*)&Ksl[sr * KP + sc + 8] = rg[3];
    *(short8*)&Vsh[sr * VP + sc] = rg[4];
    *(short8*)&Vsh[sr * VP + sc + 8] = rg[5];
    *(short8*)&Vsl[sr * VP + sc] = rg[6];
    *(short8*)&Vsl[sr * VP + sc + 8] = rg[7];
    // T14: issue next tile's global loads now; they stay in flight across
    // the raw barrier and land under this tile's compute.
    if (kt + 1 < SDIM / 64) {
      const int k1 = k0 + 64;
      rg[0] = *(const short8*)(Kh + (size_t)(k1 + sr) * DHEAD + sc);
      rg[1] = *(const short8*)(Kh + (size_t)(k1 + sr) * DHEAD + sc + 8);
      rg[2] = *(const short8*)(Kl + (size_t)(k1 + sr) * DHEAD + sc);
      rg[3] = *(const short8*)(Kl + (size_t)(k1 + sr) * DHEAD + sc + 8);
      rg[4] = *(const short8*)(Vh + (size_t)sr * SDIM + k1 + sc);
      rg[5] = *(const short8*)(Vh + (size_t)sr * SDIM + k1 + sc + 8);
      rg[6] = *(const short8*)(Vl + (size_t)sr * SDIM + k1 + sc);
      rg[7] = *(const short8*)(Vl + (size_t)sr * SDIM + k1 + sc + 8);
    }
    float mv[4];
#pragma unroll
    for (int nt = 0; nt < 4; nt++)
      mv[nt] = fmaf(mb[k0 + nt * 16 + lane15], MASKMUL, -M0C);
    // barrier B: LDS writes visible (lgkm only — vmcnt stays outstanding)
    asm volatile("s_waitcnt lgkmcnt(0)" ::: "memory");
    __builtin_amdgcn_s_barrier();
    __builtin_amdgcn_sched_barrier(0);

    __builtin_amdgcn_s_setprio(1);
#pragma unroll
    for (int mt = 0; mt < 2; mt++)
#pragma unroll
      for (int nt = 0; nt < 4; nt++) {
        f32x4 acc = (f32x4){0.f, 0.f, 0.f, 0.f};
#pragma unroll
        for (int ks = 0; ks < 2; ks++) {
          const int koff = (nt * 16 + lane15) * KP + ks * 32 + quad * 8;
          const short8 kbh = *(const short8*)&Ksh[koff];
          const short8 kbl = *(const short8*)&Ksl[koff];
          acc = MFMA16(qfh[mt][ks], kbh, acc);
          acc = MFMA16(qfh[mt][ks], kbl, acc);
          acc = MFMA16(qfl[mt][ks], kbh, acc);
        }
#pragma unroll
        for (int r = 0; r < 4; r++) {
          const float p = EXP2F(fmaf(acc[r], SCALE2, mv[nt]));
          Ps[(w * 32 + mt * 16 + quad * 4 + r) * PP + nt * 16 + lane15] = p;
        }
      }
    __builtin_amdgcn_s_setprio(0);

    short8 pah[2][2], pal[2][2];
#pragma unroll
    for (int mt = 0; mt < 2; mt++)
#pragma unroll
      for (int kf = 0; kf < 2; kf++) {
        const float* pr =
            &Ps[(w * 32 + mt * 16 + lane15) * PP + kf * 32 + quad * 8];
        const f32x4 p0 = *(const f32x4*)pr;
        const f32x4 p1 = *(const f32x4*)(pr + 4);
        short8 ph, pl;
#pragma unroll
        for (int j = 0; j < 4; j++) {
          short hh, ll;
          bf16_split(p0[j], hh, ll);
          ph[j] = hh;
          pl[j] = ll;
        }
#pragma unroll
        for (int j = 0; j < 4; j++) {
          short hh, ll;
          bf16_split(p1[j], hh, ll);
          ph[4 + j] = hh;
          pl[4 + j] = ll;
        }
        pah[mt][kf] = ph;
        pal[mt][kf] = pl;
      }

    __builtin_amdgcn_s_setprio(1);
#pragma unroll
    for (int mt = 0; mt < 2; mt++) {
      f32x4 racc = (f32x4){0.f, 0.f, 0.f, 0.f};
#pragma unroll
      for (int kf = 0; kf < 2; kf++) {
        racc = MFMA16(pah[mt][kf], onesb, racc);
        racc = MFMA16(pal[mt][kf], onesb, racc);
      }
#pragma unroll
      for (int r = 0; r < 4; r++) lr[mt][r] += racc[r];
    }

#pragma unroll
    for (int dt = 0; dt < 4; dt++)
#pragma unroll
      for (int kf = 0; kf < 2; kf++) {
        const int voff = (dt * 16 + lane15) * VP + kf * 32 + quad * 8;
        const short8 vbh = *(const short8*)&Vsh[voff];
        const short8 vbl = *(const short8*)&Vsl[voff];
#pragma unroll
        for (int mt = 0; mt < 2; mt++) {
          o[mt][dt] = MFMA16(pah[mt][kf], vbh, o[mt][dt]);
          o[mt][dt] = MFMA16(pah[mt][kf], vbl, o[mt][dt]);
          o[mt][dt] = MFMA16(pal[mt][kf], vbh, o[mt][dt]);
        }
      }
    __builtin_amdgcn_s_setprio(0);
  }

  float inv[2][4];
#pragma unroll
  for (int mt = 0; mt < 2; mt++)
#pragma unroll
    for (int r = 0; r < 4; r++) inv[mt][r] = 1.f / lr[mt][r];
#pragma unroll
  for (int mt = 0; mt < 2; mt++)
#pragma unroll
    for (int dt = 0; dt < 4; dt++)
#pragma unroll
      for (int r = 0; r < 4; r++) {
        const int q = q0 + w * 32 + mt * 16 + quad * 4 + r;
        const int col = h * DHEAD + dt * 16 + lane15;
        const float val = o[mt][dt][r] * inv[mt][r];
        short x, y;
        bf16_split(val, x, y);
        const size_t off = ((size_t)b * SDIM + q) * DMODEL + col;
        ctxh[off] = x;
        ctxl[off] = y;
      }
}

// ---------------------------------------------------------------------------
extern "C" void kernel_launch(void* const* d_in, const int* in_sizes, int n_in,
                              void* d_out, int out_size, void* d_ws,
                              size_t ws_size, hipStream_t stream) {
  const float* q = (const float*)d_in[0];
  const float* k = (const float*)d_in[1];
  const float* v = (const float*)d_in[2];
  const float* mask = (const float*)d_in[3];
  const float* Wq = (const float*)d_in[4];
  const float* bq = (const float*)d_in[5];
  const float* Wk = (const float*)d_in[6];
  const float* bk = (const float*)d_in[7];
  const float* Wv = (const float*)d_in[8];
  const float* bv = (const float*)d_in[9];
  const float* Wo = (const float*)d_in[10];
  const float* bo = (const float*)d_in[11];
  float* out = (float*)d_out;

  char* W = (char*)d_ws;
  const size_t SZB = (size_t)MROWS * DMODEL * sizeof(short);  // 8 MB
  short* q_h = (short*)(W + 0 * SZB);
  short* q_l = (short*)(W + 1 * SZB);
  short* k_h = (short*)(W + 2 * SZB);
  short* k_l = (short*)(W + 3 * SZB);
  short* v_h = (short*)(W + 4 * SZB);
  short* v_l = (short*)(W + 5 * SZB);
  short* vt_h = (short*)(W + 6 * SZB);
  short* vt_l = (short*)(W + 7 * SZB);
  // cx buffers: reused as (a) pre-split activation input per projection,
  // (b) pre-split attention context after flash.
  short* cx_h = (short*)(W + 8 * SZB);
  short* cx_l = (short*)(W + 9 * SZB);
  const size_t WSZ = (size_t)DMODEL * DMODEL * sizeof(short);  // 512 KB
  char* WT = W + 10 * SZB;
  short* wtq_h = (short*)(WT + 0 * WSZ);
  short* wtq_l = (short*)(WT + 1 * WSZ);
  short* wtk_h = (short*)(WT + 2 * WSZ);
  short* wtk_l = (short*)(WT + 3 * WSZ);
  short* wtv_h = (short*)(WT + 4 * WSZ);
  short* wtv_l = (short*)(WT + 5 * WSZ);
  short* wto_h = (short*)(WT + 6 * WSZ);
  short* wto_l = (short*)(WT + 7 * WSZ);

  wsplit_kernel<<<dim3(DMODEL / 64, DMODEL / 64, 4), 256, 0, stream>>>(
      Wq, Wk, Wv, Wo, wtq_h, wtq_l, wtk_h, wtk_l, wtv_h, wtv_l, wto_h, wto_l);

  const dim3 gx(MROWS * DMODEL / (256 * 8));    // 2048
  const dim3 gp2(MROWS / 64, DMODEL / 256);     // (128, 2)

  xsplit_kernel<<<gx, 256, 0, stream>>>(q, cx_h, cx_l);
  proj2_kernel<1><<<gp2, 512, 0, stream>>>(cx_h, cx_l, wtq_h, wtq_l, bq,
                                           nullptr, q_h, q_l);
  xsplit_kernel<<<gx, 256, 0, stream>>>(k, cx_h, cx_l);
  proj2_kernel<1><<<gp2, 512, 0, stream>>>(cx_h, cx_l, wtk_h, wtk_l, bk,
                                           nullptr, k_h, k_l);
  xsplit_kernel<<<gx, 256, 0, stream>>>(v, cx_h, cx_l);
  proj2_kernel<1><<<gp2, 512, 0, stream>>>(cx_h, cx_l, wtv_h, wtv_l, bv,
                                           nullptr, v_h, v_l);

  vtrans_kernel<<<dim3(SDIM / 64, NHEAD, BDIM), 256, 0, stream>>>(v_h, v_l,
                                                                  vt_h, vt_l);

  flash_attn_kernel<<<dim3(SDIM / 128, NHEAD, BDIM), 256, 0, stream>>>(
      q_h, q_l, k_h, k_l, vt_h, vt_l, mask, cx_h, cx_l);

  proj2_kernel<0><<<gp2, 512, 0, stream>>>(cx_h, cx_l, wto_h, wto_l, bo, out,
                                           nullptr, nullptr);
}